// Round 2
// baseline (243.038 us; speedup 1.0000x reference)
//
#include <hip/hip_runtime.h>
#include <cfloat>
#include <cmath>
#include <cstdint>

#define VV 50257
#define SPLITS 8
#define CHUNK ((VV + SPLITS - 1) / SPLITS)   // 6283
#define BMW ((CHUNK + 31) / 32)              // 197
#define NBUCK 4096
#define CAP 1024
#define K1T 256
#define K2T 1024

__device__ __forceinline__ unsigned fmono(float f) {
    unsigned b = __float_as_uint(f);
    return b ^ (((int)b < 0) ? 0xFFFFFFFFu : 0x80000000u);
}

// K1: per (row, chunk): penalty + online (max,sum) partial + local top-64
// candidate extraction via LDS histogram threshold.
__global__ __launch_bounds__(K1T) void pp_k1(
    const float* __restrict__ logits, const int* __restrict__ prev,
    const float* __restrict__ rpp,
    float* __restrict__ pm, float* __restrict__ ps,
    float* __restrict__ cand_v, int* __restrict__ cand_i,
    int* __restrict__ gcnt, int Hp, int capRow)
{
    const int sp   = blockIdx.x;
    const int row  = blockIdx.y;
    const int tid  = threadIdx.x;
    const int lane = tid & 63;
    const int wid  = tid >> 6;
    const int c0 = sp * CHUNK;
    const int c1 = min(VV, c0 + CHUNK);
    const float rp = rpp[0];
    const float inv_rp = 1.0f / rp;
    const unsigned K64 = (unsigned)min(64, c1 - c0);

    __shared__ unsigned bm[BMW];
    __shared__ unsigned hist[NBUCK];
    __shared__ float rm[K1T / 64], rs[K1T / 64];
    __shared__ unsigned wtot[K1T / 64];
    __shared__ int sT;

    for (int i = tid; i < BMW; i += K1T) bm[i] = 0u;
    for (int i = tid; i < NBUCK; i += K1T) hist[i] = 0u;
    if (tid == 0) sT = 0;
    __syncthreads();

    // chunk-local prev-token bitmap
    const int* prow = prev + (size_t)row * Hp;
    for (int i = tid; i < Hp; i += K1T) {
        int t = prow[i];
        if (t >= c0 && t < c1) {
            int o = t - c0;
            atomicOr(&bm[o >> 5], 1u << (o & 31));
        }
    }
    __syncthreads();

    // pass A: penalized value, histogram, online (max,sum)
    const float* lrow = logits + (size_t)row * VV;
    float m = -FLT_MAX, s = 0.0f;
    for (int i = c0 + tid; i < c1; i += K1T) {
        float l = lrow[i];
        int o = i - c0;
        if ((bm[o >> 5] >> (o & 31)) & 1u)
            l = (l < 0.0f) ? l * rp : l * inv_rp;
        atomicAdd(&hist[fmono(l) >> 20], 1u);
        if (l <= m) s += __expf(l - m);
        else { s = s * __expf(m - l) + 1.0f; m = l; }
    }
    #pragma unroll
    for (int off = 32; off; off >>= 1) {
        float om = __shfl_down(m, off);
        float os = __shfl_down(s, off);
        float nm = fmaxf(m, om);
        s = s * __expf(m - nm) + os * __expf(om - nm);
        m = nm;
    }
    if (lane == 0) { rm[wid] = m; rs[wid] = s; }
    __syncthreads();                 // hist complete + rm/rs visible
    if (tid == 0) {
        float M = rm[0], Ss = rs[0];
        for (int w = 1; w < K1T / 64; ++w) {
            float nm = fmaxf(M, rm[w]);
            Ss = Ss * __expf(M - nm) + rs[w] * __expf(rm[w] - nm);
            M = nm;
        }
        pm[(size_t)row * SPLITS + sp] = M;
        ps[(size_t)row * SPLITS + sp] = Ss;
    }

    // threshold: suffix-count over 4096 buckets, 16 buckets/thread
    unsigned c = 0;
    #pragma unroll
    for (int j = 0; j < 16; ++j) c += hist[tid * 16 + j];
    unsigned v = c;
    #pragma unroll
    for (int off = 1; off < 64; off <<= 1) {
        unsigned o = __shfl_down(v, off);
        if (lane + off < 64) v += o;
    }
    if (lane == 0) wtot[wid] = v;
    __syncthreads();
    unsigned add = 0;
    for (int w = wid + 1; w < K1T / 64; ++w) add += wtot[w];
    unsigned mySuf = v + add;        // suffix incl. own 16 buckets
    unsigned sufExcl = mySuf - c;    // suffix excl. own
    if (mySuf >= K64 && sufExcl < K64) {
        unsigned above = sufExcl;
        for (int b = tid * 16 + 15; b >= tid * 16; --b) {
            above += hist[b];
            if (above >= K64) { sT = b; break; }
        }
    }
    __syncthreads();
    const unsigned T = (unsigned)sT;

    // pass B (L2-hot): collect candidates >= local threshold bucket
    for (int i = c0 + tid; i < c1; i += K1T) {
        float l = lrow[i];
        int o = i - c0;
        if ((bm[o >> 5] >> (o & 31)) & 1u)
            l = (l < 0.0f) ? l * rp : l * inv_rp;
        if ((fmono(l) >> 20) >= T) {
            int p = atomicAdd(&gcnt[row], 1);
            if (p < capRow) {
                cand_v[(size_t)row * capRow + p] = l;
                cand_i[(size_t)row * capRow + p] = i;
            }
        }
    }
}

// K2: per row: merge (m,s) partials, rank-select top-64, finale.
__global__ __launch_bounds__(K2T) void pp_k2(
    const float* __restrict__ u, const float* __restrict__ toppp,
    const float* __restrict__ tempp, const int* __restrict__ topkp,
    const float* __restrict__ pm, const float* __restrict__ ps,
    const float* __restrict__ cand_v, const int* __restrict__ cand_i,
    const int* __restrict__ gcnt,
    float* __restrict__ out_idx, float* __restrict__ out_probs, int capRow)
{
    const int row = blockIdx.x;
    const int tid = threadIdx.x;
    __shared__ float cv[CAP];
    __shared__ int   cidx[CAP];
    __shared__ float tv[64];
    __shared__ int   ti[64];
    __shared__ float sM, sS;

    const int cnt = min(gcnt[row], capRow);
    if (tid < cnt) {
        cv[tid]   = cand_v[(size_t)row * capRow + tid];
        cidx[tid] = cand_i[(size_t)row * capRow + tid];
    }
    if (tid < 64) { tv[tid] = -FLT_MAX; ti[tid] = 0x7FFFFFFF; }
    if (tid == 0) {
        float M = pm[(size_t)row * SPLITS], Ss = ps[(size_t)row * SPLITS];
        for (int j = 1; j < SPLITS; ++j) {
            float m2 = pm[(size_t)row * SPLITS + j];
            float s2 = ps[(size_t)row * SPLITS + j];
            float nm = fmaxf(M, m2);
            Ss = Ss * __expf(M - nm) + s2 * __expf(m2 - nm);
            M = nm;
        }
        sM = M; sS = Ss;
    }
    __syncthreads();

    // rank selection: candidate tid's global descending rank (stable by index)
    if (tid < cnt) {
        float vi = cv[tid]; int ii = cidx[tid];
        int r = 0;
        for (int j = 0; j < cnt; ++j) {
            float vj = cv[j]; int ij = cidx[j];
            r += (int)((vj > vi) || (vj == vi && ij < ii));
        }
        if (r < 64) { tv[r] = vi; ti[r] = ii; }
    }
    __syncthreads();

    if (tid < 64) {
        const int lane = tid;
        const float top_p = toppp[0];
        const float temp = tempp[0];
        int K = topkp[0]; K = min(max(K, 1), 64);
        const float M = sM, Ssum = sS;
        float vl = tv[lane];
        int ci = ti[lane];
        bool val = (vl > -FLT_MAX);
        bool act = (lane < K) && val;
        float e = act ? expf(vl - M) / Ssum : 0.0f;
        float cum = e;
        #pragma unroll
        for (int off = 1; off < 64; off <<= 1) {
            float pv = __shfl_up(cum, off);
            if (lane >= off) cum += pv;
        }
        unsigned long long bal = __ballot(act && (cum <= top_p));
        int n = (int)__popcll(bal);
        if (n < 1) n = 1;   // rank-0 always kept
        const float v0 = tv[0];
        const float invT = 1.0f / fmaxf(temp, 1e-5f);
        bool keep = (lane < n) && val;
        float w = keep ? expf((vl - v0) * invT) : 0.0f;
        float Z = w;
        #pragma unroll
        for (int off = 32; off; off >>= 1) Z += __shfl_xor(Z, off);
        float p = keep ? (w / Z) : 0.0f;
        if (keep) out_probs[(size_t)row * VV + ci] = p;
        float ratio = -1.0f;
        if (keep) ratio = p / (-logf(u[(size_t)row * VV + ci]));
        int bi = keep ? ci : 0x7FFFFFFF;
        #pragma unroll
        for (int off = 32; off; off >>= 1) {
            float orat = __shfl_xor(ratio, off);
            int oidx = __shfl_xor(bi, off);
            if (orat > ratio || (orat == ratio && oidx < bi)) { ratio = orat; bi = oidx; }
        }
        if (lane == 0) out_idx[row] = (float)bi;
    }
}

extern "C" void kernel_launch(void* const* d_in, const int* in_sizes, int n_in,
                              void* d_out, int out_size, void* d_ws, size_t ws_size,
                              hipStream_t stream) {
    const float* logits = (const float*)d_in[0];
    const int*   prev   = (const int*)d_in[1];
    const float* u      = (const float*)d_in[2];
    const float* topp   = (const float*)d_in[3];
    const float* rp     = (const float*)d_in[4];
    const float* temp   = (const float*)d_in[5];
    const int*   topk   = (const int*)d_in[6];

    const int B  = in_sizes[0] / VV;
    const int Hp = in_sizes[1] / B;

    // workspace layout
    char* ws = (char*)d_ws;
    int*   gcnt = (int*)ws;                             // B ints
    float* pm   = (float*)(ws + 4096);                  // B*SPLITS floats
    float* ps   = pm + (size_t)B * SPLITS;              // B*SPLITS floats
    char*  cbase = ws + 16384;
    int capRow = (int)(((long long)ws_size - 16384) / (8LL * B));
    if (capRow > CAP) capRow = CAP;
    if (capRow < 64) capRow = 64;                       // ws assumed large enough
    float* cand_v = (float*)cbase;                      // B*capRow floats
    int*   cand_i = (int*)(cbase + (size_t)B * capRow * 4);

    float* out = (float*)d_out;
    // probs are sparse (<=64 nonzeros/row): zero everything, then scatter.
    hipMemsetAsync(d_out, 0, (size_t)out_size * sizeof(float), stream);
    hipMemsetAsync(gcnt, 0, (size_t)B * sizeof(int), stream);

    pp_k1<<<dim3(SPLITS, B), K1T, 0, stream>>>(
        logits, prev, rp, pm, ps, cand_v, cand_i, gcnt, Hp, capRow);
    pp_k2<<<B, K2T, 0, stream>>>(
        u, topp, temp, topk, pm, ps, cand_v, cand_i, gcnt, out, out + B, capRow);
}

// Round 3
// 33.077 us; speedup vs baseline: 7.3476x; 7.3476x over previous
//
#include <hip/hip_runtime.h>
#include <cfloat>
#include <cmath>
#include <cstdint>

#define VV 50257
#define NT 1024
#define NBUCK 4096
#define CAP 1024
#define BITW ((VV + 31) / 32)
#define NW (NT / 64)

__device__ __forceinline__ unsigned fmono(float f) {
    unsigned b = __float_as_uint(f);
    return b ^ (((int)b < 0) ? 0xFFFFFFFFu : 0x80000000u);
}

__global__ __launch_bounds__(NT) void pp_fused(
    const float* __restrict__ logits, const int* __restrict__ prev,
    const float* __restrict__ u, const float* __restrict__ toppp,
    const float* __restrict__ rpp, const float* __restrict__ tempp,
    const int* __restrict__ topkp, float* __restrict__ out_idx,
    float* __restrict__ out_probs, int Hp)
{
    __shared__ unsigned bitmap[BITW];
    __shared__ unsigned hist[NBUCK];
    __shared__ float cand_v[CAP];
    __shared__ int   cand_i[CAP];
    __shared__ float red_m[NW], red_s[NW];
    __shared__ unsigned wtot[NW];
    __shared__ float tv[64];
    __shared__ int   ti[64];
    __shared__ float sM, sS;
    __shared__ int sT, sCnt;

    const int row = blockIdx.x;
    const int tid = threadIdx.x;
    const int lane = tid & 63;
    const int wid = tid >> 6;
    const float rp = rpp[0];
    const float inv_rp = 1.0f / rp;

    for (int i = tid; i < BITW; i += NT) bitmap[i] = 0u;
    for (int i = tid; i < NBUCK; i += NT) hist[i] = 0u;
    if (tid == 0) { sT = 0; sCnt = 0; }
    if (tid < 64) { tv[tid] = -FLT_MAX; ti[tid] = 0x7FFFFFFF; }
    __syncthreads();

    // ---- prev-token bitmap (penalty idempotent w.r.t. duplicates) ----
    const int* prow = prev + (size_t)row * Hp;
    for (int i = tid; i < Hp; i += NT) {
        int t = prow[i];
        atomicOr(&bitmap[t >> 5], 1u << (t & 31));
    }
    __syncthreads();

    const float* lrow = logits + (size_t)row * VV;
    float* orow = out_probs + (size_t)row * VV;
    // row*VV ≡ row (mod 4): peel to reach 16B alignment for float4
    const int pad = (4 - (row & 3)) & 3;
    const int n4 = (VV - pad) >> 2;
    const int tail0 = pad + 4 * n4;
    const float4* lrow4 = (const float4*)(lrow + pad);
    float4* orow4 = (float4*)(orow + pad);

    // ---- pass 1: penalized max + histogram (vectorized) ----
    float m = -FLT_MAX;
    if (tid < pad) {
        float l = lrow[tid];
        if ((bitmap[tid >> 5] >> (tid & 31)) & 1u) l = (l < 0.f) ? l * rp : l * inv_rp;
        atomicAdd(&hist[fmono(l) >> 20], 1u);
        m = fmaxf(m, l);
    }
    #pragma unroll 4
    for (int k = tid; k < n4; k += NT) {
        float4 v = lrow4[k];
        const int base = pad + 4 * k;
        float e[4] = {v.x, v.y, v.z, v.w};
        #pragma unroll
        for (int j = 0; j < 4; ++j) {
            int i = base + j;
            float l = e[j];
            if ((bitmap[i >> 5] >> (i & 31)) & 1u) l = (l < 0.f) ? l * rp : l * inv_rp;
            atomicAdd(&hist[fmono(l) >> 20], 1u);
            m = fmaxf(m, l);
        }
    }
    for (int i = tail0 + tid; i < VV; i += NT) {
        float l = lrow[i];
        if ((bitmap[i >> 5] >> (i & 31)) & 1u) l = (l < 0.f) ? l * rp : l * inv_rp;
        atomicAdd(&hist[fmono(l) >> 20], 1u);
        m = fmaxf(m, l);
    }

    // ---- zero output row (float4 burst; drained at next barrier) ----
    if (tid < pad) orow[tid] = 0.0f;
    const float4 z4 = make_float4(0.f, 0.f, 0.f, 0.f);
    for (int k = tid; k < n4; k += NT) orow4[k] = z4;
    for (int i = tail0 + tid; i < VV; i += NT) orow[i] = 0.0f;

    // ---- block max ----
    #pragma unroll
    for (int off = 32; off; off >>= 1) m = fmaxf(m, __shfl_down(m, off));
    if (lane == 0) red_m[wid] = m;
    __syncthreads();   // hist complete, red_m visible, zero-stores drained
    if (tid == 0) {
        float M = red_m[0];
        for (int w = 1; w < NW; ++w) M = fmaxf(M, red_m[w]);
        sM = M;
    }

    // ---- threshold bucket: hierarchical suffix scan, 4 buckets/thread ----
    unsigned c = hist[tid * 4] + hist[tid * 4 + 1] + hist[tid * 4 + 2] + hist[tid * 4 + 3];
    unsigned v = c;
    #pragma unroll
    for (int off = 1; off < 64; off <<= 1) {
        unsigned o = __shfl_down(v, off);
        if (lane + off < 64) v += o;
    }
    if (lane == 0) wtot[wid] = v;
    __syncthreads();
    unsigned add = 0;
    for (int w = wid + 1; w < NW; ++w) add += wtot[w];
    const unsigned mySuf = v + add;
    const unsigned sufExcl = mySuf - c;
    if (mySuf >= 64u && sufExcl < 64u) {
        unsigned above = sufExcl;
        for (int b = tid * 4 + 3; b >= tid * 4; --b) {
            above += hist[b];
            if (above >= 64u) { sT = b; break; }
        }
    }
    __syncthreads();
    const unsigned T = (unsigned)sT;
    const float M = sM;

    // ---- pass 2 (L2-hot): softmax denominator + candidate collection ----
    float s = 0.0f;
    if (tid < pad) {
        float l = lrow[tid];
        if ((bitmap[tid >> 5] >> (tid & 31)) & 1u) l = (l < 0.f) ? l * rp : l * inv_rp;
        s += __expf(l - M);
        if ((fmono(l) >> 20) >= T) {
            int p = atomicAdd(&sCnt, 1);
            if (p < CAP) { cand_v[p] = l; cand_i[p] = tid; }
        }
    }
    #pragma unroll 2
    for (int k = tid; k < n4; k += NT) {
        float4 vv = lrow4[k];
        const int base = pad + 4 * k;
        float e[4] = {vv.x, vv.y, vv.z, vv.w};
        #pragma unroll
        for (int j = 0; j < 4; ++j) {
            int i = base + j;
            float l = e[j];
            if ((bitmap[i >> 5] >> (i & 31)) & 1u) l = (l < 0.f) ? l * rp : l * inv_rp;
            s += __expf(l - M);
            if ((fmono(l) >> 20) >= T) {
                int p = atomicAdd(&sCnt, 1);
                if (p < CAP) { cand_v[p] = l; cand_i[p] = i; }
            }
        }
    }
    for (int i = tail0 + tid; i < VV; i += NT) {
        float l = lrow[i];
        if ((bitmap[i >> 5] >> (i & 31)) & 1u) l = (l < 0.f) ? l * rp : l * inv_rp;
        s += __expf(l - M);
        if ((fmono(l) >> 20) >= T) {
            int p = atomicAdd(&sCnt, 1);
            if (p < CAP) { cand_v[p] = l; cand_i[p] = i; }
        }
    }
    #pragma unroll
    for (int off = 32; off; off >>= 1) s += __shfl_down(s, off);
    if (lane == 0) red_s[wid] = s;
    __syncthreads();   // sCnt, cand, red_s complete
    if (tid == 0) {
        float Ss = red_s[0];
        for (int w = 1; w < NW; ++w) Ss += red_s[w];
        sS = Ss;
    }
    const int cnt = min(sCnt, CAP);

    // ---- rank-select top-64 (replaces bitonic sort; 1 barrier) ----
    if (tid < cnt) {
        float vi = cand_v[tid]; int ii = cand_i[tid];
        int r = 0;
        for (int j = 0; j < cnt; ++j) {
            float vj = cand_v[j]; int ij = cand_i[j];
            r += (int)((vj > vi) || (vj == vi && ij < ii));
        }
        if (r < 64) { tv[r] = vi; ti[r] = ii; }
    }
    __syncthreads();

    // ---- finale: top-p cutoff, temperature softmax, scatter, gumbel argmax ----
    if (tid < 64) {
        const float top_p = toppp[0];
        const float temp = tempp[0];
        int K = topkp[0]; K = min(max(K, 1), 64);
        const float Ssum = sS;
        float vl = tv[lane];
        int ci = ti[lane];
        bool val = (vl > -FLT_MAX);
        bool act = (lane < K) && val;
        float e = act ? expf(vl - M) / Ssum : 0.0f;
        float cum = e;
        #pragma unroll
        for (int off = 1; off < 64; off <<= 1) {
            float pv = __shfl_up(cum, off);
            if (lane >= off) cum += pv;
        }
        unsigned long long bal = __ballot(act && (cum <= top_p));
        int n = (int)__popcll(bal);
        if (n < 1) n = 1;   // rank-0 always kept
        const float v0 = tv[0];
        const float invT = 1.0f / fmaxf(temp, 1e-5f);
        bool keep = (lane < n) && val;
        float w = keep ? expf((vl - v0) * invT) : 0.0f;
        float Z = w;
        #pragma unroll
        for (int off = 32; off; off >>= 1) Z += __shfl_xor(Z, off);
        float p = keep ? (w / Z) : 0.0f;
        if (keep) orow[ci] = p;
        float ratio = -1.0f;
        if (keep) ratio = p / (-logf(u[(size_t)row * VV + ci]));
        int bi = keep ? ci : 0x7FFFFFFF;
        #pragma unroll
        for (int off = 32; off; off >>= 1) {
            float orat = __shfl_xor(ratio, off);
            int oidx = __shfl_xor(bi, off);
            if (orat > ratio || (orat == ratio && oidx < bi)) { ratio = orat; bi = oidx; }
        }
        if (lane == 0) out_idx[row] = (float)bi;
    }
}

extern "C" void kernel_launch(void* const* d_in, const int* in_sizes, int n_in,
                              void* d_out, int out_size, void* d_ws, size_t ws_size,
                              hipStream_t stream) {
    const float* logits = (const float*)d_in[0];
    const int*   prev   = (const int*)d_in[1];
    const float* u      = (const float*)d_in[2];
    const float* topp   = (const float*)d_in[3];
    const float* rp     = (const float*)d_in[4];
    const float* temp   = (const float*)d_in[5];
    const int*   topk   = (const int*)d_in[6];

    const int B  = in_sizes[0] / VV;
    const int Hp = in_sizes[1] / B;

    float* out = (float*)d_out;
    // single fused kernel; output zeroing happens in-kernel (no memset dispatch)
    pp_fused<<<B, NT, 0, stream>>>(
        logits, prev, u, topp, rp, temp, topk, out, out + B, Hp);
}